// Round 3
// baseline (419.788 us; speedup 1.0000x reference)
//
#include <hip/hip_runtime.h>

// x (16,8,512,512) fp32. Per (b,c) row of 2^18 elems: 1%/99% linear-interp
// quantiles -> th = i1+(i99-i1)*alpha; out = relu(x)*sigmoid(beta/th_new*(|x|-th*mask)).
//
// R3: 3-kernel pipeline, full-GPU parallelism everywhere that touches HBM.
//  k_hist : 8 blocks/row (1024 blocks), LDS hist, global atomic merge (nonzero bins)
//  k_qsel : 1 block/row, scan hist -> collect candidates (L3 re-read) -> radix select
//  k_out  : 16 blocks/row, wave-uniform th, native exp2+rcp gate

#define ROWS 128
#define NPR  262144      // 2^18 per row
#define BINS 8192        // top-13 bits of sortable key
#define SHIFT 19
#define CAP  4096
#define HTPB 256
#define HBPR 8
#define QTPB 1024
#define OTPB 256

// rank targets: 0.01*262143 = 2621.43 ; 0.99*262143 = 259521.57
#define K_LO 2621u
#define K_HI 259521u

__device__ __forceinline__ unsigned keyOf(float f) {
    unsigned u = __float_as_uint(f);
    return (u & 0x80000000u) ? ~u : (u | 0x80000000u);
}
__device__ __forceinline__ float keyToFloat(unsigned k) {
    unsigned u = (k & 0x80000000u) ? (k & 0x7fffffffu) : ~k;
    return __uint_as_float(u);
}

__global__ __launch_bounds__(HTPB) void k_hist(const float* __restrict__ x,
                                               unsigned* __restrict__ gh) {
    __shared__ unsigned lh[BINS];
    for (int i = threadIdx.x; i < BINS; i += HTPB) lh[i] = 0;
    __syncthreads();
    const int row = blockIdx.x >> 3;
    const int blk = blockIdx.x & 7;
    const float4* xr = (const float4*)(x + (size_t)row * NPR + (size_t)blk * (NPR / HBPR));
    const int NV = NPR / HBPR / 4;   // 8192 float4
    for (int i = threadIdx.x; i < NV; i += HTPB) {
        float4 v = xr[i];
        atomicAdd(&lh[keyOf(v.x) >> SHIFT], 1u);
        atomicAdd(&lh[keyOf(v.y) >> SHIFT], 1u);
        atomicAdd(&lh[keyOf(v.z) >> SHIFT], 1u);
        atomicAdd(&lh[keyOf(v.w) >> SHIFT], 1u);
    }
    __syncthreads();
    unsigned* h = gh + (size_t)row * BINS;
    for (int i = threadIdx.x; i < BINS; i += HTPB) {
        unsigned c = lh[i];
        if (c) atomicAdd(&h[i], c);
    }
}

__global__ __launch_bounds__(QTPB) void k_qsel(const float* __restrict__ x,
                                               const unsigned* __restrict__ gh,
                                               float* __restrict__ qv) {
    const int row = blockIdx.x;
    const int tid = threadIdx.x;
    const float4* xr = (const float4*)(x + (size_t)row * NPR);

    __shared__ unsigned smem[BINS];                 // hist copy, then cand[2][CAP]
    unsigned (*cand)[CAP] = (unsigned(*)[CAP])smem;
    __shared__ unsigned part[256];
    __shared__ unsigned sh[256];
    __shared__ unsigned sb[8];      // blo0,bhi0,cb0, blo1,bhi1,cb1
    __shared__ unsigned svar[4];
    __shared__ unsigned ccnt[2];

    // ---- stage hist to LDS (coalesced) ----
    const unsigned* h = gh + (size_t)row * BINS;
    for (int i = tid; i < BINS; i += QTPB) smem[i] = h[i];
    __syncthreads();

    // ---- scan: locate bins holding ranks {K_LO,K_LO+1,K_HI,K_HI+1} ----
    const int CH = BINS / 256;   // 32
    if (tid < 256) {
        unsigned s = 0;
        int base = tid * CH;
        for (int i = 0; i < CH; ++i) s += smem[base + i];
        part[tid] = s;
    }
    __syncthreads();
    if (tid == 0) {
        unsigned run = 0;
        for (int t = 0; t < 256; ++t) { unsigned tmp = part[t]; part[t] = run; run += tmp; }
    }
    __syncthreads();
    if (tid < 256) {
        unsigned cum = part[tid];
        int base = tid * CH;
        const unsigned targets[4] = {K_LO, K_LO + 1u, K_HI, K_HI + 1u};
        for (int i = 0; i < CH; ++i) {
            unsigned c = smem[base + i];
            if (c) {
                #pragma unroll
                for (int t = 0; t < 4; ++t) {
                    if (targets[t] >= cum && targets[t] < cum + c) {
                        if      (t == 0) { sb[0] = base + i; sb[2] = cum; }
                        else if (t == 1) { sb[1] = base + i; }
                        else if (t == 2) { sb[3] = base + i; sb[5] = cum; }
                        else             { sb[4] = base + i; }
                    }
                }
            }
            cum += c;
        }
    }
    if (tid < 2) ccnt[tid] = 0;
    __syncthreads();   // sb done; smem free for cand

    // ---- collect candidate keys (row is L3-resident) ----
    {
        unsigned blo0 = sb[0], bhi0 = sb[1], blo1 = sb[3], bhi1 = sb[4];
        const int NV = NPR / 4;
        for (int i = tid; i < NV; i += QTPB) {
            float4 v = xr[i];
            float vv[4] = {v.x, v.y, v.z, v.w};
            #pragma unroll
            for (int j = 0; j < 4; ++j) {
                unsigned key = keyOf(vv[j]);
                unsigned bin = key >> SHIFT;
                if (bin >= blo0 && bin <= bhi0) {
                    unsigned p = atomicAdd(&ccnt[0], 1u);
                    if (p < CAP) cand[0][p] = key;
                }
                if (bin >= blo1 && bin <= bhi1) {
                    unsigned p = atomicAdd(&ccnt[1], 1u);
                    if (p < CAP) cand[1][p] = key;
                }
            }
        }
    }
    __syncthreads();

    // ---- 4-pass byte-radix select for ranks t and t+1 ----
    for (int iq = 0; iq < 2; ++iq) {
        unsigned m = ccnt[iq]; if (m > CAP) m = CAP;
        unsigned cb = iq ? sb[5] : sb[2];
        unsigned t_lo = (iq ? K_HI : K_LO) - cb;
        unsigned prefix = 0, trem = t_lo, cntEq = 0;
        for (int p = 3; p >= 0; --p) {
            for (int i = tid; i < 256; i += QTPB) sh[i] = 0;
            __syncthreads();
            for (unsigned i = tid; i < m; i += QTPB) {
                unsigned key = cand[iq][i];
                bool match = (p == 3) || ((key >> ((p + 1) * 8)) == (prefix >> ((p + 1) * 8)));
                if (match) atomicAdd(&sh[(key >> (p * 8)) & 255u], 1u);
            }
            __syncthreads();
            if (tid == 0) {
                unsigned cum = 0;
                for (int b = 0; b < 256; ++b) {
                    unsigned c = sh[b];
                    if (trem >= cum && trem < cum + c) { svar[0] = (unsigned)b; svar[1] = cum; svar[2] = c; break; }
                    cum += c;
                }
            }
            __syncthreads();
            prefix |= svar[0] << (p * 8);
            trem   -= svar[1];
            cntEq   = svar[2];
            __syncthreads();
        }
        unsigned vlo_key = prefix;
        unsigned cntLess = t_lo - trem;
        unsigned vhi_key;
        if (t_lo + 1u < cntLess + cntEq) {
            vhi_key = vlo_key;
        } else {
            if (tid == 0) svar[3] = 0xFFFFFFFFu;
            __syncthreads();
            for (unsigned i = tid; i < m; i += QTPB) {
                unsigned key = cand[iq][i];
                if (key > vlo_key) atomicMin(&svar[3], key);
            }
            __syncthreads();
            vhi_key = svar[3];
        }
        if (tid == 0) {
            double frac = iq ? (0.99 * (double)(NPR - 1) - (double)K_HI)
                             : (0.01 * (double)(NPR - 1) - (double)K_LO);
            double vlo = (double)keyToFloat(vlo_key);
            double vhi = (double)keyToFloat(vhi_key);
            qv[row * 2 + iq] = (float)(vlo + (vhi - vlo) * frac);
        }
        __syncthreads();
    }
}

__global__ __launch_bounds__(OTPB) void k_out(const float* __restrict__ x,
                                              const float* __restrict__ alpha,
                                              const float* __restrict__ beta,
                                              const float* __restrict__ qv,
                                              float* __restrict__ out) {
    const int row = blockIdx.x >> 4;     // 16 blocks per row, wave-uniform th
    float q0 = qv[row * 2], q1 = qv[row * 2 + 1];
    float a = alpha[0], bt = beta[0];
    float th = q0 + (q1 - q0) * a;
    bool  msk = th > 1e-14f;
    float thn = msk ? th : 1.0f;
    float thm = msk ? th : 0.0f;
    float nsc = -(bt / thn) * 1.4426950408889634f;   // -beta/th_new * log2(e)
    const float4* xv = (const float4*)x + (size_t)blockIdx.x * 4096;
    float4*       ov = (float4*)out     + (size_t)blockIdx.x * 4096;
    #pragma unroll 4
    for (int k = 0; k < 16; ++k) {
        int i = k * OTPB + threadIdx.x;
        float4 v = xv[i];
        float4 o;
        o.x = v.x > 0.f ? v.x * __builtin_amdgcn_rcpf(1.f + __builtin_amdgcn_exp2f(nsc * (fabsf(v.x) - thm))) : 0.f;
        o.y = v.y > 0.f ? v.y * __builtin_amdgcn_rcpf(1.f + __builtin_amdgcn_exp2f(nsc * (fabsf(v.y) - thm))) : 0.f;
        o.z = v.z > 0.f ? v.z * __builtin_amdgcn_rcpf(1.f + __builtin_amdgcn_exp2f(nsc * (fabsf(v.z) - thm))) : 0.f;
        o.w = v.w > 0.f ? v.w * __builtin_amdgcn_rcpf(1.f + __builtin_amdgcn_exp2f(nsc * (fabsf(v.w) - thm))) : 0.f;
        ov[i] = o;
    }
}

extern "C" void kernel_launch(void* const* d_in, const int* in_sizes, int n_in,
                              void* d_out, int out_size, void* d_ws, size_t ws_size,
                              hipStream_t stream) {
    const float* x     = (const float*)d_in[0];
    const float* alpha = (const float*)d_in[1];
    const float* beta  = (const float*)d_in[2];
    float* out = (float*)d_out;
    unsigned* gh = (unsigned*)d_ws;                    // 128*8192 u32 = 4 MB
    float* qv = (float*)(gh + (size_t)ROWS * BINS);    // 256 floats
    hipMemsetAsync(gh, 0, (size_t)ROWS * BINS * sizeof(unsigned), stream);
    k_hist<<<ROWS * HBPR, HTPB, 0, stream>>>(x, gh);
    k_qsel<<<ROWS,        QTPB, 0, stream>>>(x, gh, qv);
    k_out <<<ROWS * 16,   OTPB, 0, stream>>>(x, alpha, beta, qv, out);
}

// Round 4
// 357.159 us; speedup vs baseline: 1.1754x; 1.1754x over previous
//
#include <hip/hip_runtime.h>

// x (16,8,512,512) fp32. Per (b,c) row of 2^18 elems: 1%/99% linear-interp
// quantiles -> th = i1+(i99-i1)*alpha; out = relu(x)*sigmoid(beta/th_new*(|x|-th*mask)).
//
// R4: 5-kernel pipeline, full-GPU parallelism, no contended global atomics.
//  k_hist    : 256 blocks (2/row, 1024thr), LDS hist, PLAIN coalesced partial-hist stores
//  k_scan    : 128 blocks, sum 2 partials/row, locate target bins -> key ranges
//  k_collect : 2048 blocks (16/row), LDS compaction, 1 atomicAdd/block/quantile
//  k_select  : 256 blocks, byte-radix select on <=4096 candidates
//  k_out     : 2048 blocks, wave-uniform th, native exp2+rcp gate

#define ROWS 128
#define NPR  262144
#define BINS 8192
#define SHIFT 19
#define CAP  4096
#define CBUF 2048        // per-block candidate buffer (expected ~165/slice; 2048 = huge margin)

// rank targets: 0.01*262143 = 2621.43 ; 0.99*262143 = 259521.57
#define K_LO 2621u
#define K_HI 259521u

// ws layout (u32 units)
#define OFF_GH   0
#define OFF_GCNT (ROWS*2*BINS)          // 256 counters
#define OFF_SB   (OFF_GCNT + 256)       // 128*8 range info
#define OFF_CAND (OFF_SB + ROWS*8)      // 128*2*CAP keys
#define OFF_QV   (OFF_CAND + ROWS*2*CAP)

__device__ __forceinline__ unsigned keyOf(float f) {
    unsigned u = __float_as_uint(f);
    return (u & 0x80000000u) ? ~u : (u | 0x80000000u);
}
__device__ __forceinline__ float keyToFloat(unsigned k) {
    unsigned u = (k & 0x80000000u) ? (k & 0x7fffffffu) : ~k;
    return __uint_as_float(u);
}

__global__ __launch_bounds__(1024) void k_hist(const float* __restrict__ x,
                                               unsigned* __restrict__ gh) {
    __shared__ unsigned lh[BINS];
    for (int i = threadIdx.x; i < BINS; i += 1024) lh[i] = 0;
    __syncthreads();
    const int row  = blockIdx.x >> 1;
    const int half = blockIdx.x & 1;
    const float4* xr = (const float4*)(x + (size_t)row * NPR + (size_t)half * (NPR / 2));
    const int NV = NPR / 2 / 4;   // 32768 float4
    for (int i = threadIdx.x; i < NV; i += 1024) {
        float4 v = xr[i];
        atomicAdd(&lh[keyOf(v.x) >> SHIFT], 1u);
        atomicAdd(&lh[keyOf(v.y) >> SHIFT], 1u);
        atomicAdd(&lh[keyOf(v.z) >> SHIFT], 1u);
        atomicAdd(&lh[keyOf(v.w) >> SHIFT], 1u);
    }
    __syncthreads();
    unsigned* h = gh + (size_t)blockIdx.x * BINS;   // plain partial-hist store
    for (int i = threadIdx.x; i < BINS; i += 1024) h[i] = lh[i];
}

__global__ __launch_bounds__(256) void k_scan(const unsigned* __restrict__ gh,
                                              unsigned* __restrict__ sbinfo) {
    const int row = blockIdx.x;
    const int tid = threadIdx.x;
    const unsigned* h0 = gh + (size_t)(row * 2) * BINS;
    const unsigned* h1 = h0 + BINS;
    __shared__ unsigned part[256];
    __shared__ unsigned sb[8];
    const int CH = BINS / 256;   // 32 bins/thread
    int base = tid * CH;
    unsigned loc[CH];
    unsigned s = 0;
    #pragma unroll
    for (int i = 0; i < CH; ++i) { loc[i] = h0[base + i] + h1[base + i]; s += loc[i]; }
    part[tid] = s;
    __syncthreads();
    if (tid == 0) {
        unsigned run = 0;
        for (int t = 0; t < 256; ++t) { unsigned tmp = part[t]; part[t] = run; run += tmp; }
    }
    __syncthreads();
    {
        unsigned cum = part[tid];
        const unsigned targets[4] = {K_LO, K_LO + 1u, K_HI, K_HI + 1u};
        for (int i = 0; i < CH; ++i) {
            unsigned c = loc[i];
            if (c) {
                #pragma unroll
                for (int t = 0; t < 4; ++t) {
                    if (targets[t] >= cum && targets[t] < cum + c) {
                        if      (t == 0) { sb[0] = base + i; sb[2] = cum; }
                        else if (t == 1) { sb[1] = base + i; }
                        else if (t == 2) { sb[3] = base + i; sb[5] = cum; }
                        else             { sb[4] = base + i; }
                    }
                }
            }
            cum += c;
        }
    }
    __syncthreads();
    if (tid == 0) {
        unsigned* r = sbinfo + row * 8;
        r[0] = sb[0] << SHIFT;                 // klo0
        r[1] = ((sb[1] + 1u) << SHIFT) - 1u;   // khi0 (wraps to 0xFFFFFFFF at bin 8191: correct)
        r[2] = sb[2];                          // count below klo0
        r[3] = sb[3] << SHIFT;                 // klo1
        r[4] = ((sb[4] + 1u) << SHIFT) - 1u;   // khi1
        r[5] = sb[5];                          // count below klo1
    }
}

__global__ __launch_bounds__(256) void k_collect(const float* __restrict__ x,
                                                 const unsigned* __restrict__ sbinfo,
                                                 unsigned* __restrict__ gcnt,
                                                 unsigned* __restrict__ candg) {
    __shared__ unsigned buf0[CBUF], buf1[CBUF];
    __shared__ unsigned lc[2];
    __shared__ unsigned gbase[2];
    const int row = blockIdx.x >> 4;
    const int blk = blockIdx.x & 15;
    if (threadIdx.x < 2) lc[threadIdx.x] = 0;
    __syncthreads();
    const unsigned* r = sbinfo + row * 8;
    const unsigned klo0 = r[0], khi0 = r[1], klo1 = r[3], khi1 = r[4];
    const float4* xr = (const float4*)(x + (size_t)row * NPR + (size_t)blk * (NPR / 16));
    const int NV = NPR / 16 / 4;   // 4096 float4
    for (int i = threadIdx.x; i < NV; i += 256) {
        float4 v = xr[i];
        float vv[4] = {v.x, v.y, v.z, v.w};
        #pragma unroll
        for (int j = 0; j < 4; ++j) {
            unsigned key = keyOf(vv[j]);
            if (key >= klo0 && key <= khi0) {
                unsigned p = atomicAdd(&lc[0], 1u);
                if (p < CBUF) buf0[p] = key;
            }
            if (key >= klo1 && key <= khi1) {
                unsigned p = atomicAdd(&lc[1], 1u);
                if (p < CBUF) buf1[p] = key;
            }
        }
    }
    __syncthreads();
    if (threadIdx.x < 2) {
        unsigned n = lc[threadIdx.x]; if (n > CBUF) n = CBUF;
        gbase[threadIdx.x] = atomicAdd(&gcnt[row * 2 + threadIdx.x], n);
    }
    __syncthreads();
    unsigned n0 = lc[0] > CBUF ? CBUF : lc[0];
    unsigned n1 = lc[1] > CBUF ? CBUF : lc[1];
    unsigned* c0 = candg + (size_t)(row * 2) * CAP;
    unsigned* c1 = c0 + CAP;
    for (unsigned i = threadIdx.x; i < n0; i += 256) {
        unsigned p = gbase[0] + i; if (p < CAP) c0[p] = buf0[i];
    }
    for (unsigned i = threadIdx.x; i < n1; i += 256) {
        unsigned p = gbase[1] + i; if (p < CAP) c1[p] = buf1[i];
    }
}

__global__ __launch_bounds__(256) void k_select(const unsigned* __restrict__ candg,
                                                const unsigned* __restrict__ gcnt,
                                                const unsigned* __restrict__ sbinfo,
                                                float* __restrict__ qv) {
    const int rq  = blockIdx.x;    // row*2 + iq
    const int row = rq >> 1;
    const int iq  = rq & 1;
    const int tid = threadIdx.x;
    __shared__ unsigned keys[CAP];
    __shared__ unsigned sh[256];
    __shared__ unsigned svar[4];
    unsigned m = gcnt[rq]; if (m > CAP) m = CAP;
    const unsigned* cand = candg + (size_t)rq * CAP;
    for (unsigned i = tid; i < m; i += 256) keys[i] = cand[i];
    __syncthreads();

    const unsigned cb   = sbinfo[row * 8 + (iq ? 5 : 2)];
    const unsigned t_lo = (iq ? K_HI : K_LO) - cb;
    unsigned prefix = 0, trem = t_lo, cntEq = 0;
    for (int p = 3; p >= 0; --p) {
        sh[tid] = 0;
        __syncthreads();
        for (unsigned i = tid; i < m; i += 256) {
            unsigned key = keys[i];
            bool match = (p == 3) || ((key >> ((p + 1) * 8)) == (prefix >> ((p + 1) * 8)));
            if (match) atomicAdd(&sh[(key >> (p * 8)) & 255u], 1u);
        }
        __syncthreads();
        if (tid == 0) {
            unsigned cum = 0;
            for (int b = 0; b < 256; ++b) {
                unsigned c = sh[b];
                if (trem >= cum && trem < cum + c) { svar[0] = (unsigned)b; svar[1] = cum; svar[2] = c; break; }
                cum += c;
            }
        }
        __syncthreads();
        prefix |= svar[0] << (p * 8);
        trem   -= svar[1];
        cntEq   = svar[2];
        __syncthreads();
    }
    unsigned vlo_key = prefix;
    unsigned cntLess = t_lo - trem;
    unsigned vhi_key;
    if (t_lo + 1u < cntLess + cntEq) {
        vhi_key = vlo_key;                     // duplicate covers rank t+1
    } else {
        if (tid == 0) svar[3] = 0xFFFFFFFFu;
        __syncthreads();
        for (unsigned i = tid; i < m; i += 256) {
            unsigned key = keys[i];
            if (key > vlo_key) atomicMin(&svar[3], key);
        }
        __syncthreads();
        vhi_key = svar[3];
    }
    if (tid == 0) {
        double frac = iq ? (0.99 * (double)(NPR - 1) - (double)K_HI)
                         : (0.01 * (double)(NPR - 1) - (double)K_LO);
        double vlo = (double)keyToFloat(vlo_key);
        double vhi = (double)keyToFloat(vhi_key);
        qv[rq] = (float)(vlo + (vhi - vlo) * frac);
    }
}

__global__ __launch_bounds__(256) void k_out(const float* __restrict__ x,
                                             const float* __restrict__ alpha,
                                             const float* __restrict__ beta,
                                             const float* __restrict__ qv,
                                             float* __restrict__ out) {
    const int row = blockIdx.x >> 4;     // 16 blocks/row, wave-uniform th
    float q0 = qv[row * 2], q1 = qv[row * 2 + 1];
    float a = alpha[0], bt = beta[0];
    float th = q0 + (q1 - q0) * a;
    bool  msk = th > 1e-14f;
    float thn = msk ? th : 1.0f;
    float thm = msk ? th : 0.0f;
    float nsc = -(bt / thn) * 1.4426950408889634f;   // -beta/th_new * log2(e)
    const float4* xv = (const float4*)x + (size_t)blockIdx.x * 4096;
    float4*       ov = (float4*)out     + (size_t)blockIdx.x * 4096;
    #pragma unroll 4
    for (int k = 0; k < 16; ++k) {
        int i = k * 256 + threadIdx.x;
        float4 v = xv[i];
        float4 o;
        o.x = v.x > 0.f ? v.x * __builtin_amdgcn_rcpf(1.f + __builtin_amdgcn_exp2f(nsc * (fabsf(v.x) - thm))) : 0.f;
        o.y = v.y > 0.f ? v.y * __builtin_amdgcn_rcpf(1.f + __builtin_amdgcn_exp2f(nsc * (fabsf(v.y) - thm))) : 0.f;
        o.z = v.z > 0.f ? v.z * __builtin_amdgcn_rcpf(1.f + __builtin_amdgcn_exp2f(nsc * (fabsf(v.z) - thm))) : 0.f;
        o.w = v.w > 0.f ? v.w * __builtin_amdgcn_rcpf(1.f + __builtin_amdgcn_exp2f(nsc * (fabsf(v.w) - thm))) : 0.f;
        ov[i] = o;
    }
}

extern "C" void kernel_launch(void* const* d_in, const int* in_sizes, int n_in,
                              void* d_out, int out_size, void* d_ws, size_t ws_size,
                              hipStream_t stream) {
    const float* x     = (const float*)d_in[0];
    const float* alpha = (const float*)d_in[1];
    const float* beta  = (const float*)d_in[2];
    float* out = (float*)d_out;
    unsigned* ws = (unsigned*)d_ws;
    unsigned* gh     = ws + OFF_GH;     // 8 MB partial hists (no zeroing needed)
    unsigned* gcnt   = ws + OFF_GCNT;   // 256 counters
    unsigned* sbinfo = ws + OFF_SB;
    unsigned* candg  = ws + OFF_CAND;
    float*    qv     = (float*)(ws + OFF_QV);
    hipMemsetAsync(gcnt, 0, 256 * sizeof(unsigned), stream);
    k_hist   <<<ROWS * 2,  1024, 0, stream>>>(x, gh);
    k_scan   <<<ROWS,      256,  0, stream>>>(gh, sbinfo);
    k_collect<<<ROWS * 16, 256,  0, stream>>>(x, sbinfo, gcnt, candg);
    k_select <<<ROWS * 2,  256,  0, stream>>>(candg, gcnt, sbinfo, qv);
    k_out    <<<ROWS * 16, 256,  0, stream>>>(x, alpha, beta, qv, out);
}

// Round 6
// 354.668 us; speedup vs baseline: 1.1836x; 1.0070x over previous
//
#include <hip/hip_runtime.h>

// x (16,8,512,512) fp32. Per (b,c) row of 2^18 elems: 1%/99% linear-interp
// quantiles -> th = i1+(i99-i1)*alpha; out = relu(x)*sigmoid(beta/th_new*(|x|-th*mask)).
//
// R6 (= R5 with nontemporal-store fix): 5 dispatches.
//  k_hist    : 256 blocks (2/row, 1024thr), dual LDS sub-hist, plain partial stores
//  k_scan    : 128 blocks, sum partials, locate target bins -> key ranges; zeroes gcnt
//  k_collect : 2048 blocks (16/row), LDS compaction, 1 global atomicAdd/block/quantile
//  k_select  : 256 blocks, byte-radix select on <=4096 candidates
//  k_out     : 2048 blocks, wave-uniform th, native exp2+rcp, nontemporal stores

#define ROWS 128
#define NPR  262144
#define BINS 8192
#define SHIFT 19
#define CAP  4096
#define CBUF 2048

// rank targets: 0.01*262143 = 2621.43 ; 0.99*262143 = 259521.57
#define K_LO 2621u
#define K_HI 259521u

// ws layout (u32 units)
#define OFF_GH   0
#define OFF_GCNT (ROWS*2*BINS)
#define OFF_SB   (OFF_GCNT + 256)
#define OFF_CAND (OFF_SB + ROWS*8)
#define OFF_QV   (OFF_CAND + ROWS*2*CAP)

typedef float  f32x4 __attribute__((ext_vector_type(4)));

__device__ __forceinline__ unsigned keyOf(float f) {
    unsigned u = __float_as_uint(f);
    return (u & 0x80000000u) ? ~u : (u | 0x80000000u);
}
__device__ __forceinline__ float keyToFloat(unsigned k) {
    unsigned u = (k & 0x80000000u) ? (k & 0x7fffffffu) : ~k;
    return __uint_as_float(u);
}

__global__ __launch_bounds__(1024) void k_hist(const float* __restrict__ x,
                                               unsigned* __restrict__ gh) {
    __shared__ unsigned lh[2][BINS];          // 64 KB, two sub-hists
    unsigned* flat = &lh[0][0];
    for (int i = threadIdx.x; i < 2 * BINS; i += 1024) flat[i] = 0;
    __syncthreads();
    unsigned* myh = lh[threadIdx.x >> 9];     // waves 0-7 -> copy 0, 8-15 -> copy 1
    const int row  = blockIdx.x >> 1;
    const int half = blockIdx.x & 1;
    const float4* xr = (const float4*)(x + (size_t)row * NPR + (size_t)half * (NPR / 2));
    const int NV = NPR / 2 / 4;   // 32768 float4
    for (int i = threadIdx.x; i < NV; i += 1024) {
        float4 v = xr[i];
        atomicAdd(&myh[keyOf(v.x) >> SHIFT], 1u);
        atomicAdd(&myh[keyOf(v.y) >> SHIFT], 1u);
        atomicAdd(&myh[keyOf(v.z) >> SHIFT], 1u);
        atomicAdd(&myh[keyOf(v.w) >> SHIFT], 1u);
    }
    __syncthreads();
    unsigned* h = gh + (size_t)blockIdx.x * BINS;
    for (int i = threadIdx.x; i < BINS; i += 1024) h[i] = lh[0][i] + lh[1][i];
}

__global__ __launch_bounds__(256) void k_scan(const unsigned* __restrict__ gh,
                                              unsigned* __restrict__ sbinfo,
                                              unsigned* __restrict__ gcnt) {
    const int row = blockIdx.x;
    const int tid = threadIdx.x;
    if (tid < 2) gcnt[row * 2 + tid] = 0;     // replaces host-side memset
    const unsigned* h0 = gh + (size_t)(row * 2) * BINS;
    const unsigned* h1 = h0 + BINS;
    __shared__ unsigned part[256];
    __shared__ unsigned sb[8];
    const int CH = BINS / 256;   // 32 bins/thread
    int base = tid * CH;
    unsigned loc[CH];
    unsigned s = 0;
    #pragma unroll
    for (int i = 0; i < CH; ++i) { loc[i] = h0[base + i] + h1[base + i]; s += loc[i]; }
    part[tid] = s;
    __syncthreads();
    if (tid == 0) {
        unsigned run = 0;
        for (int t = 0; t < 256; ++t) { unsigned tmp = part[t]; part[t] = run; run += tmp; }
    }
    __syncthreads();
    {
        unsigned cum = part[tid];
        const unsigned targets[4] = {K_LO, K_LO + 1u, K_HI, K_HI + 1u};
        #pragma unroll
        for (int i = 0; i < CH; ++i) {
            unsigned c = loc[i];
            if (c) {
                #pragma unroll
                for (int t = 0; t < 4; ++t) {
                    if (targets[t] >= cum && targets[t] < cum + c) {
                        if      (t == 0) { sb[0] = base + i; sb[2] = cum; }
                        else if (t == 1) { sb[1] = base + i; }
                        else if (t == 2) { sb[3] = base + i; sb[5] = cum; }
                        else             { sb[4] = base + i; }
                    }
                }
            }
            cum += c;
        }
    }
    __syncthreads();
    if (tid == 0) {
        unsigned* r = sbinfo + row * 8;
        r[0] = sb[0] << SHIFT;
        r[1] = ((sb[1] + 1u) << SHIFT) - 1u;   // wrap at bin 8191 -> 0xFFFFFFFF: correct
        r[2] = sb[2];
        r[3] = sb[3] << SHIFT;
        r[4] = ((sb[4] + 1u) << SHIFT) - 1u;
        r[5] = sb[5];
    }
}

__global__ __launch_bounds__(256) void k_collect(const float* __restrict__ x,
                                                 const unsigned* __restrict__ sbinfo,
                                                 unsigned* __restrict__ gcnt,
                                                 unsigned* __restrict__ candg) {
    __shared__ unsigned buf0[CBUF], buf1[CBUF];
    __shared__ unsigned lc[2];
    __shared__ unsigned gbase[2];
    const int row = blockIdx.x >> 4;
    const int blk = blockIdx.x & 15;
    if (threadIdx.x < 2) lc[threadIdx.x] = 0;
    __syncthreads();
    const unsigned* r = sbinfo + row * 8;
    const unsigned klo0 = r[0], khi0 = r[1], klo1 = r[3], khi1 = r[4];
    const float4* xr = (const float4*)(x + (size_t)row * NPR + (size_t)blk * (NPR / 16));
    const int NV = NPR / 16 / 4;   // 4096 float4
    for (int i = threadIdx.x; i < NV; i += 256) {
        float4 v = xr[i];
        float vv[4] = {v.x, v.y, v.z, v.w};
        #pragma unroll
        for (int j = 0; j < 4; ++j) {
            unsigned key = keyOf(vv[j]);
            if (key >= klo0 && key <= khi0) {
                unsigned p = atomicAdd(&lc[0], 1u);
                if (p < CBUF) buf0[p] = key;
            }
            if (key >= klo1 && key <= khi1) {
                unsigned p = atomicAdd(&lc[1], 1u);
                if (p < CBUF) buf1[p] = key;
            }
        }
    }
    __syncthreads();
    if (threadIdx.x < 2) {
        unsigned n = lc[threadIdx.x]; if (n > CBUF) n = CBUF;
        gbase[threadIdx.x] = atomicAdd(&gcnt[row * 2 + threadIdx.x], n);
    }
    __syncthreads();
    unsigned n0 = lc[0] > CBUF ? CBUF : lc[0];
    unsigned n1 = lc[1] > CBUF ? CBUF : lc[1];
    unsigned* c0 = candg + (size_t)(row * 2) * CAP;
    unsigned* c1 = c0 + CAP;
    for (unsigned i = threadIdx.x; i < n0; i += 256) {
        unsigned p = gbase[0] + i; if (p < CAP) c0[p] = buf0[i];
    }
    for (unsigned i = threadIdx.x; i < n1; i += 256) {
        unsigned p = gbase[1] + i; if (p < CAP) c1[p] = buf1[i];
    }
}

__global__ __launch_bounds__(256) void k_select(const unsigned* __restrict__ candg,
                                                const unsigned* __restrict__ gcnt,
                                                const unsigned* __restrict__ sbinfo,
                                                float* __restrict__ qv) {
    const int rq  = blockIdx.x;    // row*2 + iq
    const int row = rq >> 1;
    const int iq  = rq & 1;
    const int tid = threadIdx.x;
    __shared__ unsigned keys[CAP];
    __shared__ unsigned sh[256];
    __shared__ unsigned svar[4];
    unsigned m = gcnt[rq]; if (m > CAP) m = CAP;
    const unsigned* cand = candg + (size_t)rq * CAP;
    for (unsigned i = tid; i < m; i += 256) keys[i] = cand[i];
    __syncthreads();

    const unsigned cb   = sbinfo[row * 8 + (iq ? 5 : 2)];
    const unsigned t_lo = (iq ? K_HI : K_LO) - cb;
    unsigned prefix = 0, trem = t_lo, cntEq = 0;
    for (int p = 3; p >= 0; --p) {
        sh[tid] = 0;
        __syncthreads();
        for (unsigned i = tid; i < m; i += 256) {
            unsigned key = keys[i];
            bool match = (p == 3) || ((key >> ((p + 1) * 8)) == (prefix >> ((p + 1) * 8)));
            if (match) atomicAdd(&sh[(key >> (p * 8)) & 255u], 1u);
        }
        __syncthreads();
        if (tid == 0) {
            unsigned cum = 0;
            for (int b = 0; b < 256; ++b) {
                unsigned c = sh[b];
                if (trem >= cum && trem < cum + c) { svar[0] = (unsigned)b; svar[1] = cum; svar[2] = c; break; }
                cum += c;
            }
        }
        __syncthreads();
        prefix |= svar[0] << (p * 8);
        trem   -= svar[1];
        cntEq   = svar[2];
        __syncthreads();
    }
    unsigned vlo_key = prefix;
    unsigned cntLess = t_lo - trem;
    unsigned vhi_key;
    if (t_lo + 1u < cntLess + cntEq) {
        vhi_key = vlo_key;
    } else {
        if (tid == 0) svar[3] = 0xFFFFFFFFu;
        __syncthreads();
        for (unsigned i = tid; i < m; i += 256) {
            unsigned key = keys[i];
            if (key > vlo_key) atomicMin(&svar[3], key);
        }
        __syncthreads();
        vhi_key = svar[3];
    }
    if (tid == 0) {
        double frac = iq ? (0.99 * (double)(NPR - 1) - (double)K_HI)
                         : (0.01 * (double)(NPR - 1) - (double)K_LO);
        double vlo = (double)keyToFloat(vlo_key);
        double vhi = (double)keyToFloat(vhi_key);
        qv[rq] = (float)(vlo + (vhi - vlo) * frac);
    }
}

__global__ __launch_bounds__(256) void k_out(const float* __restrict__ x,
                                             const float* __restrict__ alpha,
                                             const float* __restrict__ beta,
                                             const float* __restrict__ qv,
                                             float* __restrict__ out) {
    const int row = blockIdx.x >> 4;     // 16 blocks/row, wave-uniform th
    float q0 = qv[row * 2], q1 = qv[row * 2 + 1];
    float a = alpha[0], bt = beta[0];
    float th = q0 + (q1 - q0) * a;
    bool  msk = th > 1e-14f;
    float thn = msk ? th : 1.0f;
    float thm = msk ? th : 0.0f;
    float nsc = -(bt / thn) * 1.4426950408889634f;   // -beta/th_new * log2(e)
    const float4* xv = (const float4*)x + (size_t)blockIdx.x * 4096;
    f32x4*        ov = (f32x4*)out      + (size_t)blockIdx.x * 4096;
    #pragma unroll 8
    for (int k = 0; k < 16; ++k) {
        int i = k * 256 + threadIdx.x;
        float4 v = xv[i];
        f32x4 o;
        o.x = v.x > 0.f ? v.x * __builtin_amdgcn_rcpf(1.f + __builtin_amdgcn_exp2f(nsc * (fabsf(v.x) - thm))) : 0.f;
        o.y = v.y > 0.f ? v.y * __builtin_amdgcn_rcpf(1.f + __builtin_amdgcn_exp2f(nsc * (fabsf(v.y) - thm))) : 0.f;
        o.z = v.z > 0.f ? v.z * __builtin_amdgcn_rcpf(1.f + __builtin_amdgcn_exp2f(nsc * (fabsf(v.z) - thm))) : 0.f;
        o.w = v.w > 0.f ? v.w * __builtin_amdgcn_rcpf(1.f + __builtin_amdgcn_exp2f(nsc * (fabsf(v.w) - thm))) : 0.f;
        __builtin_nontemporal_store(o, &ov[i]);
    }
}

extern "C" void kernel_launch(void* const* d_in, const int* in_sizes, int n_in,
                              void* d_out, int out_size, void* d_ws, size_t ws_size,
                              hipStream_t stream) {
    const float* x     = (const float*)d_in[0];
    const float* alpha = (const float*)d_in[1];
    const float* beta  = (const float*)d_in[2];
    float* out = (float*)d_out;
    unsigned* ws = (unsigned*)d_ws;
    unsigned* gh     = ws + OFF_GH;
    unsigned* gcnt   = ws + OFF_GCNT;
    unsigned* sbinfo = ws + OFF_SB;
    unsigned* candg  = ws + OFF_CAND;
    float*    qv     = (float*)(ws + OFF_QV);
    k_hist   <<<ROWS * 2,  1024, 0, stream>>>(x, gh);
    k_scan   <<<ROWS,      256,  0, stream>>>(gh, sbinfo, gcnt);
    k_collect<<<ROWS * 16, 256,  0, stream>>>(x, sbinfo, gcnt, candg);
    k_select <<<ROWS * 2,  256,  0, stream>>>(candg, gcnt, sbinfo, qv);
    k_out    <<<ROWS * 16, 256,  0, stream>>>(x, alpha, beta, qv, out);
}